// Round 6
// baseline (2290.321 us; speedup 1.0000x reference)
//
#include <hip/hip_runtime.h>
#include <hip/hip_bf16.h>

typedef __hip_bfloat16 bf16;
typedef unsigned short u16x8 __attribute__((ext_vector_type(8)));
using v8s = __attribute__((ext_vector_type(8))) short;   // bf16 x8 MFMA frag (4 VGPR)
using v4f = __attribute__((ext_vector_type(4))) float;   // f32 x4 acc frag

#define L_SEQ 2048
#define BATCH 8
#define NIN   1024    // 2H
#define WLD   3072    // W row stride, layers 1-3
#define NHALF 1536    // per-direction columns (3*H)
#define NROWS (L_SEQ*BATCH)

__device__ __forceinline__ float bits2f(unsigned short u){ return __uint_as_float(((unsigned)u)<<16); }
__device__ __forceinline__ float b2f(bf16 v){ return __bfloat162float(v); }
__device__ __forceinline__ bf16  f2b(float v){ return __float2bfloat16(v); }
__device__ __forceinline__ float sigm(float z){ return __fdividef(1.0f, 1.0f + __expf(-z)); }

__device__ __forceinline__ void gload16(const void* g, void* l){
    __builtin_amdgcn_global_load_lds((const __attribute__((address_space(1))) void*)g,
                                     (__attribute__((address_space(3))) void*)l, 16, 0, 0);
}

__global__ void k_code(float* __restrict__ out, float v){
    if (threadIdx.x == 0 && blockIdx.x == 0) out[0] = v;
}

// ---------------- dxT[b][l] = X[b][l] - X[b][l-1], 0 at l=0  ((B,L) layout)
__global__ __launch_bounds__(256) void k_diff(const float* __restrict__ X, float* __restrict__ dxT){
    int i = blockIdx.x*256 + threadIdx.x;
    if (i >= NROWS) return;
    int l = i & (L_SEQ-1);
    float v = 0.f;
    if (l > 0) v = X[i] - X[i-1];
    dxT[i] = v;
}

// ---------------- W (fp32 [1024][3072]) -> Wt (bf16 [3072][1024], transposed)
__global__ __launch_bounds__(256) void k_wt(const float* __restrict__ W, bf16* __restrict__ Wt){
    __shared__ float t[32][33];
    int k0 = blockIdx.x*32, n0 = blockIdx.y*32;
    int tx = threadIdx.x & 31, ty = threadIdx.x >> 5;   // ty 0..7
    #pragma unroll
    for (int j=0;j<4;j++)
        t[ty*4+j][tx] = W[(size_t)(k0+ty*4+j)*WLD + n0 + tx];
    __syncthreads();
    #pragma unroll
    for (int j=0;j<4;j++)
        Wt[(size_t)(n0+ty*4+j)*NIN + k0 + tx] = f2b(t[tx][ty*4+j]);
}

// ---------------- layer 0 (n_in=1, k=4): outer-product U, fused; LDS-staged dx + 8-ahead prefetch
__global__ __launch_bounds__(256) void k_layer0(const float* __restrict__ dxT, const float* __restrict__ W0,
                                                const float* __restrict__ wc, const float* __restrict__ bb,
                                                bf16* __restrict__ xout){
    __shared__ float sdx[L_SEQ];
    int g = blockIdx.x*256 + threadIdx.x;           // 8192 threads: (d,b,h); b,d block-uniform
    int h = g & 511, b = (g>>9) & 7, d = g >> 12;
    const float* dxp = dxT + b*L_SEQ;
    for (int t = threadIdx.x; t < L_SEQ; t += 256) sdx[t] = dxp[t];
    __syncthreads();

    int dcol = d*512 + h;
    float w0 = W0[d*2048 + h];
    float w1 = W0[d*2048 + 512 + h];
    float w2 = W0[d*2048 + 1024 + h];
    float w3 = W0[d*2048 + 1536 + h];
    float vf = wc[dcol],  vr = wc[1024 + dcol];
    float bfv = bb[dcol], brv = bb[1024 + dcol];
    float c = 0.f;

#define LD0(buf, s0) do{                                             \
        _Pragma("unroll")                                            \
        for (int i_=0;i_<8;i_++){                                    \
            int ss_ = (s0)+i_; if (ss_ > L_SEQ-1) ss_ = L_SEQ-1;     \
            buf[i_] = sdx[d ? (L_SEQ-1-ss_) : ss_];                  \
        } }while(0)

#define STEP0(s_, xv_) do{                                           \
        float u0_ = (xv_)*w0;                                        \
        float f_ = sigm((xv_)*w1 + vf*c + bfv);                      \
        c = f_*c + (1.f-f_)*u0_;                                     \
        float r_ = sigm((xv_)*w2 + vr*c + brv);                      \
        float hv_ = r_*c + (1.f-r_)*((xv_)*w3);                      \
        int t_ = d ? (L_SEQ-1-(s_)) : (s_);                          \
        xout[((size_t)t_*BATCH + b)*NIN + dcol] = f2b(hv_);          \
    }while(0)

    float xa[8], xb[8];
    LD0(xa, 0);
    for (int s0 = 0; s0 < L_SEQ; s0 += 16){
        LD0(xb, s0+8);
        #pragma unroll
        for (int i=0;i<8;i++) STEP0(s0+i, xa[i]);
        LD0(xa, s0+16);
        #pragma unroll
        for (int i=0;i<8;i++) STEP0(s0+8+i, xb[i]);
    }
#undef LD0
#undef STEP0
}

// ---------------- MFMA GEMM: Uc[set s] = x[chunk rows] @ Wt[set s]^T  (unchanged from round 5)
__global__ __launch_bounds__(256) void k_gemm(const bf16* __restrict__ Xin, const bf16* __restrict__ Wt,
                                              float* __restrict__ Uc, int l0, int C){
    __shared__ bf16 As[4096];   // [128 m][32 k], 64B rows
    __shared__ bf16 Bs[4096];   // [128 n][32 k]
    int tid = threadIdx.x;
    int lane = tid & 63;
    int s = blockIdx.z;
    int base = (s == 0) ? l0 : (L_SEQ - l0 - C);
    const bf16* A  = Xin + (size_t)base*BATCH*NIN;
    const bf16* Bm = Wt + (size_t)s*NHALF*NIN;
    float*      Cc = Uc + (size_t)s*(size_t)C*BATCH*NHALF;

    int m0 = blockIdx.x*128, n0 = blockIdx.y*128;
    int wv = tid >> 6;                  // wave 0..3
    int wm = (wv >> 1)*64, wn = (wv & 1)*64;

    v4f acc[4][4];
    #pragma unroll
    for (int i=0;i<4;i++)
        #pragma unroll
        for (int j=0;j<4;j++)
            #pragma unroll
            for (int r=0;r<4;r++) acc[i][j][r] = 0.f;

    int row_a = tid >> 2, kb = (tid & 3)*8;
    int wbase = (tid & 192)*16;                    // wave-uniform lds byte base
    char* ldsA = (char*)As;
    char* ldsB = (char*)Bs;
    int fro = (lane & 15)*64 + (lane >> 4)*16;

    for (int k0 = 0; k0 < NIN; k0 += 32){
        gload16(A  + (size_t)(m0 + row_a      )*NIN + k0 + kb, ldsA + wbase);
        gload16(A  + (size_t)(m0 + row_a + 64 )*NIN + k0 + kb, ldsA + 4096 + wbase);
        gload16(Bm + (size_t)(n0 + row_a      )*NIN + k0 + kb, ldsB + wbase);
        gload16(Bm + (size_t)(n0 + row_a + 64 )*NIN + k0 + kb, ldsB + 4096 + wbase);
        __syncthreads();
        v8s av[4], bv[4];
        #pragma unroll
        for (int i=0;i<4;i++) av[i] = *(const v8s*)(ldsA + (wm + i*16)*64 + fro);
        #pragma unroll
        for (int j=0;j<4;j++) bv[j] = *(const v8s*)(ldsB + (wn + j*16)*64 + fro);
        #pragma unroll
        for (int i=0;i<4;i++)
            #pragma unroll
            for (int j=0;j<4;j++)
                acc[i][j] = __builtin_amdgcn_mfma_f32_16x16x32_bf16(av[i], bv[j], acc[i][j], 0, 0, 0);
        __syncthreads();
    }
    int cr = (lane >> 4)*4, ccol = lane & 15;
    #pragma unroll
    for (int i=0;i<4;i++){
        #pragma unroll
        for (int j=0;j<4;j++){
            size_t rb = (size_t)(m0 + wm + i*16 + cr)*NHALF + (n0 + wn + j*16 + ccol);
            #pragma unroll
            for (int r=0;r<4;r++) Cc[rb + (size_t)r*NHALF] = acc[i][j][r];
        }
    }
}

// ---------------- recurrence, layers 1-3 (k=3): 16-step groups, 16-ahead register prefetch
__global__ __launch_bounds__(64) void k_rec(const float* __restrict__ Uc, const bf16* __restrict__ xin,
                                            bf16* __restrict__ xout, float* __restrict__ carry,
                                            const float* __restrict__ wc, const float* __restrict__ bb,
                                            int l0, int C){
    int g = blockIdx.x*64 + threadIdx.x;            // 8192 channels: (d,b,h)
    int h = g & 511, b = (g>>9) & 7, d = g >> 12;
    int dcol = d*512 + h;
    float vf = wc[dcol],   vr = wc[1024 + dcol];
    float bfv = bb[dcol],  brv = bb[1024 + dcol];
    float c = (l0 == 0) ? 0.f : carry[g];
    const float* Us = Uc + (size_t)d*(size_t)C*12288 + (size_t)b*NHALF + h;

#define LOADG(b0,b1,b2,br,s0) do{                                    \
        _Pragma("unroll")                                            \
        for (int i_=0;i_<16;i_++){                                   \
            int ss_ = (s0)+i_; if (ss_ > C-1) ss_ = C-1;             \
            int row_ = d ? (C-1-ss_) : ss_;                          \
            const float* up_ = Us + (size_t)row_*12288;              \
            b0[i_] = up_[0]; b1[i_] = up_[512]; b2[i_] = up_[1024];  \
            int t_ = d ? (L_SEQ-1 - l0 - ss_) : (l0 + ss_);          \
            br[i_] = b2f(xin[((size_t)t_*BATCH + b)*NIN + dcol]);    \
        } }while(0)

#define STEPG(b0,b1,b2,br,s0) do{                                    \
        _Pragma("unroll")                                            \
        for (int i_=0;i_<16;i_++){                                   \
            float f_ = sigm(b1[i_] + vf*c + bfv);                    \
            c = f_*c + (1.f-f_)*b0[i_];                              \
            float r_ = sigm(b2[i_] + vr*c + brv);                    \
            float hv_ = r_*c + (1.f-r_)*br[i_];                      \
            int t_ = d ? (L_SEQ-1 - l0 - ((s0)+i_)) : (l0 + (s0)+i_);\
            xout[((size_t)t_*BATCH + b)*NIN + dcol] = f2b(hv_);      \
        } }while(0)

    float A0[16],A1[16],A2[16],AR[16];
    float B0[16],B1[16],B2[16],BR[16];
    LOADG(A0,A1,A2,AR, 0);
    for (int s0 = 0; s0 < C; s0 += 32){
        LOADG(B0,B1,B2,BR, s0+16);
        STEPG(A0,A1,A2,AR, s0);
        LOADG(A0,A1,A2,AR, s0+32);
        STEPG(B0,B1,B2,BR, s0+16);
    }
    carry[g] = c;
#undef LOADG
#undef STEPG
}

// ---------------- classifier: out[(b*L + l)*3 + j] = h[row l*8+b] @ Wcls + bcls
__global__ __launch_bounds__(256) void k_cls(const bf16* __restrict__ Xf, const float* __restrict__ Wc,
                                             const float* __restrict__ bc, float* __restrict__ out){
    int wave = threadIdx.x >> 6, lane = threadIdx.x & 63;
    int row = blockIdx.x*4 + wave;                  // row = l*8+b
    const bf16* xp = Xf + (size_t)row*NIN + lane*16;
    u16x8 v0 = *(const u16x8*)(xp);
    u16x8 v1 = *(const u16x8*)(xp + 8);
    float a0=0.f, a1=0.f, a2=0.f;
    #pragma unroll
    for (int i=0;i<16;i++){
        float xv = bits2f(i<8 ? v0[i&7] : v1[i&7]);
        int k = lane*16 + i;
        a0 += xv*Wc[k*3+0];
        a1 += xv*Wc[k*3+1];
        a2 += xv*Wc[k*3+2];
    }
    #pragma unroll
    for (int off=32; off; off>>=1){
        a0 += __shfl_down(a0, off);
        a1 += __shfl_down(a1, off);
        a2 += __shfl_down(a2, off);
    }
    if (lane == 0){
        int l = row >> 3, b = row & 7;
        float* op = out + ((size_t)b*L_SEQ + l)*3;
        op[0] = a0 + bc[0];
        op[1] = a1 + bc[1];
        op[2] = a2 + bc[2];
    }
}

// ----------------------------------------------------------------
extern "C" void kernel_launch(void* const* d_in, const int* in_sizes, int n_in,
                              void* d_out, int out_size, void* d_ws, size_t ws_size,
                              hipStream_t stream){
    (void)in_sizes; (void)n_in; (void)out_size;
    const float* X    = (const float*)d_in[0];
    const float* W[4]  = {(const float*)d_in[1],(const float*)d_in[4],(const float*)d_in[7],(const float*)d_in[10]};
    const float* wc[4] = {(const float*)d_in[2],(const float*)d_in[5],(const float*)d_in[8],(const float*)d_in[11]};
    const float* bb[4] = {(const float*)d_in[3],(const float*)d_in[6],(const float*)d_in[9],(const float*)d_in[12]};
    const float* Wcls = (const float*)d_in[13];
    const float* bcls = (const float*)d_in[14];
    float* out = (float*)d_out;

    // workspace layout:
    //   xA    bf16[16384*1024]  @ 0           33,554,432
    //   xB    bf16[16384*1024]  @ 33554432    33,554,432
    //   dxT   f32 [8*2048]      @ 67108864        65,536
    //   carry f32 [8192]        @ 67174400        32,768
    //   Wt0-2 bf16[3072*1024]   @ 67207168    3 x 6,291,456
    //   Ucb   f32 [C*2*8*1536]  @ 86081536    C*98,304   (C: 32..2048)
    char*  ws    = (char*)d_ws;
    bf16*  xA    = (bf16*)ws;
    bf16*  xB    = (bf16*)(ws + 33554432);
    float* dxT   = (float*)(ws + 67108864);
    float* carry = (float*)(ws + 67174400);
    bf16*  Wt[3] = {(bf16*)(ws + 67207168), (bf16*)(ws + 73498624), (bf16*)(ws + 79790080)};
    float* Ucb   = (float*)(ws + 86081536);
    const size_t NEEDED = 86081536ull + 32ull*98304ull;

    if (ws_size < NEEDED){
        float code = 1.0e6f + (float)((ws_size >> 20) > 9999 ? 9999 : (ws_size >> 20)) * 100.0f;
        k_code<<<1, 64, 0, stream>>>(out, code);
        return;
    }

    int C = 2048;
    while (C > 32 && 86081536ull + (size_t)C*98304ull > ws_size) C >>= 1;

    k_diff  <<<(NROWS+255)/256, 256, 0, stream>>>(X, dxT);
    for (int i = 0; i < 3; ++i)
        k_wt<<<dim3(32,96), 256, 0, stream>>>(W[i+1], Wt[i]);
    k_layer0<<<32, 256, 0, stream>>>(dxT, W[0], wc[0], bb[0], xA);

    bf16* xin = xA; bf16* xo = xB;
    for (int layer = 1; layer < 4; ++layer){
        for (int l0 = 0; l0 < L_SEQ; l0 += C){
            dim3 g(C*8/128, NHALF/128, 2);
            k_gemm<<<g, 256, 0, stream>>>(xin, Wt[layer-1], Ucb, l0, C);
            k_rec <<<128, 64, 0, stream>>>(Ucb, xin, xo, carry, wc[layer], bb[layer], l0, C);
        }
        bf16* t = xin; xin = xo; xo = t;
    }
    k_cls<<<NROWS/4, 256, 0, stream>>>(xin, Wcls, bcls, out);
}

// Round 7
// 2122.670 us; speedup vs baseline: 1.0790x; 1.0790x over previous
//
#include <hip/hip_runtime.h>
#include <hip/hip_bf16.h>

typedef __hip_bfloat16 bf16;
typedef unsigned short u16x8 __attribute__((ext_vector_type(8)));
using v8s = __attribute__((ext_vector_type(8))) short;   // bf16 x8 MFMA frag (4 VGPR)
using v4f = __attribute__((ext_vector_type(4))) float;   // f32 x4 acc frag

#define L_SEQ 2048
#define BATCH 8
#define NIN   1024    // 2H
#define WLD   3072    // W row stride, layers 1-3
#define NHALF 1536    // per-direction columns (3*H)
#define NROWS (L_SEQ*BATCH)

__device__ __forceinline__ float bits2f(unsigned short u){ return __uint_as_float(((unsigned)u)<<16); }
__device__ __forceinline__ float b2f(bf16 v){ return __bfloat162float(v); }
__device__ __forceinline__ bf16  f2b(float v){ return __float2bfloat16(v); }
__device__ __forceinline__ float sigm(float z){ return __fdividef(1.0f, 1.0f + __expf(-z)); }

__device__ __forceinline__ void gload16(const void* g, void* l){
    __builtin_amdgcn_global_load_lds((const __attribute__((address_space(1))) void*)g,
                                     (__attribute__((address_space(3))) void*)l, 16, 0, 0);
}

__global__ void k_code(float* __restrict__ out, float v){
    if (threadIdx.x == 0 && blockIdx.x == 0) out[0] = v;
}

// ---------------- dxT[b][l] = X[b][l] - X[b][l-1], 0 at l=0  ((B,L) layout)
__global__ __launch_bounds__(256) void k_diff(const float* __restrict__ X, float* __restrict__ dxT){
    int i = blockIdx.x*256 + threadIdx.x;
    if (i >= NROWS) return;
    int l = i & (L_SEQ-1);
    float v = 0.f;
    if (l > 0) v = X[i] - X[i-1];
    dxT[i] = v;
}

// ---------------- W (fp32 [1024][3072]) -> Wt (bf16 [3072][1024], transposed)
__global__ __launch_bounds__(256) void k_wt(const float* __restrict__ W, bf16* __restrict__ Wt){
    __shared__ float t[32][33];
    int k0 = blockIdx.x*32, n0 = blockIdx.y*32;
    int tx = threadIdx.x & 31, ty = threadIdx.x >> 5;   // ty 0..7
    #pragma unroll
    for (int j=0;j<4;j++)
        t[ty*4+j][tx] = W[(size_t)(k0+ty*4+j)*WLD + n0 + tx];
    __syncthreads();
    #pragma unroll
    for (int j=0;j<4;j++)
        Wt[(size_t)(n0+ty*4+j)*NIN + k0 + tx] = f2b(t[tx][ty*4+j]);
}

// ---------------- layer 0 (n_in=1, k=4): outer-product U, fused; LDS-staged dx + 8-ahead prefetch
__global__ __launch_bounds__(256) void k_layer0(const float* __restrict__ dxT, const float* __restrict__ W0,
                                                const float* __restrict__ wc, const float* __restrict__ bb,
                                                bf16* __restrict__ xout){
    __shared__ float sdx[L_SEQ];
    int g = blockIdx.x*256 + threadIdx.x;           // 8192 threads: (d,b,h); b,d block-uniform
    int h = g & 511, b = (g>>9) & 7, d = g >> 12;
    const float* dxp = dxT + b*L_SEQ;
    for (int t = threadIdx.x; t < L_SEQ; t += 256) sdx[t] = dxp[t];
    __syncthreads();

    int dcol = d*512 + h;
    float w0 = W0[d*2048 + h];
    float w1 = W0[d*2048 + 512 + h];
    float w2 = W0[d*2048 + 1024 + h];
    float w3 = W0[d*2048 + 1536 + h];
    float vf = wc[dcol],  vr = wc[1024 + dcol];
    float bfv = bb[dcol], brv = bb[1024 + dcol];
    float c = 0.f;

#define LD0(buf, s0) do{                                             \
        _Pragma("unroll")                                            \
        for (int i_=0;i_<8;i_++){                                    \
            int ss_ = (s0)+i_; if (ss_ > L_SEQ-1) ss_ = L_SEQ-1;     \
            buf[i_] = sdx[d ? (L_SEQ-1-ss_) : ss_];                  \
        } }while(0)

#define STEP0(s_, xv_) do{                                           \
        float u0_ = (xv_)*w0;                                        \
        float f_ = sigm((xv_)*w1 + vf*c + bfv);                      \
        c = f_*c + (1.f-f_)*u0_;                                     \
        float r_ = sigm((xv_)*w2 + vr*c + brv);                      \
        float hv_ = r_*c + (1.f-r_)*((xv_)*w3);                      \
        int t_ = d ? (L_SEQ-1-(s_)) : (s_);                          \
        xout[((size_t)t_*BATCH + b)*NIN + dcol] = f2b(hv_);          \
    }while(0)

    float xa[8], xb[8];
    LD0(xa, 0);
    for (int s0 = 0; s0 < L_SEQ; s0 += 16){
        LD0(xb, s0+8);
        #pragma unroll
        for (int i=0;i<8;i++) STEP0(s0+i, xa[i]);
        LD0(xa, s0+16);
        #pragma unroll
        for (int i=0;i<8;i++) STEP0(s0+8+i, xb[i]);
    }
#undef LD0
#undef STEP0
}

// ---------------- MFMA GEMM: Uc[set s] = x[chunk rows] @ Wt[set s]^T  (unchanged)
__global__ __launch_bounds__(256) void k_gemm(const bf16* __restrict__ Xin, const bf16* __restrict__ Wt,
                                              float* __restrict__ Uc, int l0, int C){
    __shared__ bf16 As[4096];   // [128 m][32 k], 64B rows
    __shared__ bf16 Bs[4096];   // [128 n][32 k]
    int tid = threadIdx.x;
    int lane = tid & 63;
    int s = blockIdx.z;
    int base = (s == 0) ? l0 : (L_SEQ - l0 - C);
    const bf16* A  = Xin + (size_t)base*BATCH*NIN;
    const bf16* Bm = Wt + (size_t)s*NHALF*NIN;
    float*      Cc = Uc + (size_t)s*(size_t)C*BATCH*NHALF;

    int m0 = blockIdx.x*128, n0 = blockIdx.y*128;
    int wv = tid >> 6;                  // wave 0..3
    int wm = (wv >> 1)*64, wn = (wv & 1)*64;

    v4f acc[4][4];
    #pragma unroll
    for (int i=0;i<4;i++)
        #pragma unroll
        for (int j=0;j<4;j++)
            #pragma unroll
            for (int r=0;r<4;r++) acc[i][j][r] = 0.f;

    int row_a = tid >> 2, kb = (tid & 3)*8;
    int wbase = (tid & 192)*16;                    // wave-uniform lds byte base
    char* ldsA = (char*)As;
    char* ldsB = (char*)Bs;
    int fro = (lane & 15)*64 + (lane >> 4)*16;

    for (int k0 = 0; k0 < NIN; k0 += 32){
        gload16(A  + (size_t)(m0 + row_a      )*NIN + k0 + kb, ldsA + wbase);
        gload16(A  + (size_t)(m0 + row_a + 64 )*NIN + k0 + kb, ldsA + 4096 + wbase);
        gload16(Bm + (size_t)(n0 + row_a      )*NIN + k0 + kb, ldsB + wbase);
        gload16(Bm + (size_t)(n0 + row_a + 64 )*NIN + k0 + kb, ldsB + 4096 + wbase);
        __syncthreads();
        v8s av[4], bv[4];
        #pragma unroll
        for (int i=0;i<4;i++) av[i] = *(const v8s*)(ldsA + (wm + i*16)*64 + fro);
        #pragma unroll
        for (int j=0;j<4;j++) bv[j] = *(const v8s*)(ldsB + (wn + j*16)*64 + fro);
        #pragma unroll
        for (int i=0;i<4;i++)
            #pragma unroll
            for (int j=0;j<4;j++)
                acc[i][j] = __builtin_amdgcn_mfma_f32_16x16x32_bf16(av[i], bv[j], acc[i][j], 0, 0, 0);
        __syncthreads();
    }
    int cr = (lane >> 4)*4, ccol = lane & 15;
    #pragma unroll
    for (int i=0;i<4;i++){
        #pragma unroll
        for (int j=0;j<4;j++){
            size_t rb = (size_t)(m0 + wm + i*16 + cr)*NHALF + (n0 + wn + j*16 + ccol);
            #pragma unroll
            for (int r=0;r<4;r++) Cc[rb + (size_t)r*NHALF] = acc[i][j][r];
        }
    }
}

// ---------------- recurrence, layers 1-3 (k=3): clamp-free affine streams, 16-ahead prefetch,
// sched_barrier pins load issue before the dependent chain (compiler sank them in round 6: VGPR=60)
__global__ __launch_bounds__(64) void k_rec(const float* __restrict__ Uc, const bf16* __restrict__ xin,
                                            bf16* __restrict__ xout, float* __restrict__ carry,
                                            const float* __restrict__ wc, const float* __restrict__ bb,
                                            int l0, int C){
    int g = blockIdx.x*64 + threadIdx.x;            // 8192 channels: (d,b,h)
    int h = g & 511, b = (g>>9) & 7, d = g >> 12;
    int dcol = d*512 + h;
    float vf = wc[dcol],   vr = wc[1024 + dcol];
    float bfv = bb[dcol],  brv = bb[1024 + dcol];
    float c = (l0 == 0) ? 0.f : carry[g];

    // step-s streams: U row walk +/-12288 floats, x walk +/-8192 bf16
    const float* u0p = Uc + (size_t)d*(size_t)C*12288 + (size_t)b*NHALF + h
                          + (d ? (size_t)(C-1)*12288 : 0);
    ptrdiff_t us = d ? -12288 : 12288;
    int t0 = d ? (L_SEQ-1 - l0) : l0;
    const bf16* xp = xin  + ((size_t)t0*BATCH + b)*NIN + dcol;
    bf16*       xq = xout + ((size_t)t0*BATCH + b)*NIN + dcol;
    ptrdiff_t xs = d ? -(BATCH*NIN) : (BATCH*NIN);

#define LOADG(B0,B1,B2,BR,s0) do{                                    \
        _Pragma("unroll")                                            \
        for (int i_=0;i_<16;i_++){                                   \
            const float* up_ = u0p + (ptrdiff_t)((s0)+i_)*us;        \
            B0[i_] = up_[0]; B1[i_] = up_[512]; B2[i_] = up_[1024];  \
            BR[i_] = b2f(xp[(ptrdiff_t)((s0)+i_)*xs]);               \
        }                                                            \
        __builtin_amdgcn_sched_barrier(0);                           \
    }while(0)

#define STEPG(B0,B1,B2,BR,s0) do{                                    \
        _Pragma("unroll")                                            \
        for (int i_=0;i_<16;i_++){                                   \
            float f_ = sigm(B1[i_] + vf*c + bfv);                    \
            c = f_*c + (1.f-f_)*B0[i_];                              \
            float r_ = sigm(B2[i_] + vr*c + brv);                    \
            float hv_ = r_*c + (1.f-r_)*BR[i_];                      \
            xq[(ptrdiff_t)((s0)+i_)*xs] = f2b(hv_);                  \
        } }while(0)

    float A0[16],A1[16],A2[16],AR[16];
    float B0[16],B1[16],B2[16],BR[16];
    LOADG(A0,A1,A2,AR, 0);
    int s0 = 0;
    for (; s0 + 64 <= C; s0 += 32){
        LOADG(B0,B1,B2,BR, s0+16);
        STEPG(A0,A1,A2,AR, s0);
        LOADG(A0,A1,A2,AR, s0+32);
        STEPG(B0,B1,B2,BR, s0+16);
    }
    // tail: A holds [C-32, C-16); load final 16 and finish (C is a multiple of 32, >= 64)
    LOADG(B0,B1,B2,BR, C-16);
    STEPG(A0,A1,A2,AR, C-32);
    STEPG(B0,B1,B2,BR, C-16);
    carry[g] = c;
#undef LOADG
#undef STEPG
}

// ---------------- classifier: out[(b*L + l)*3 + j] = h[row l*8+b] @ Wcls + bcls
__global__ __launch_bounds__(256) void k_cls(const bf16* __restrict__ Xf, const float* __restrict__ Wc,
                                             const float* __restrict__ bc, float* __restrict__ out){
    int wave = threadIdx.x >> 6, lane = threadIdx.x & 63;
    int row = blockIdx.x*4 + wave;                  // row = l*8+b
    const bf16* xp = Xf + (size_t)row*NIN + lane*16;
    u16x8 v0 = *(const u16x8*)(xp);
    u16x8 v1 = *(const u16x8*)(xp + 8);
    float a0=0.f, a1=0.f, a2=0.f;
    #pragma unroll
    for (int i=0;i<16;i++){
        float xv = bits2f(i<8 ? v0[i&7] : v1[i&7]);
        int k = lane*16 + i;
        a0 += xv*Wc[k*3+0];
        a1 += xv*Wc[k*3+1];
        a2 += xv*Wc[k*3+2];
    }
    #pragma unroll
    for (int off=32; off; off>>=1){
        a0 += __shfl_down(a0, off);
        a1 += __shfl_down(a1, off);
        a2 += __shfl_down(a2, off);
    }
    if (lane == 0){
        int l = row >> 3, b = row & 7;
        float* op = out + ((size_t)b*L_SEQ + l)*3;
        op[0] = a0 + bc[0];
        op[1] = a1 + bc[1];
        op[2] = a2 + bc[2];
    }
}

// ----------------------------------------------------------------
extern "C" void kernel_launch(void* const* d_in, const int* in_sizes, int n_in,
                              void* d_out, int out_size, void* d_ws, size_t ws_size,
                              hipStream_t stream){
    (void)in_sizes; (void)n_in; (void)out_size;
    const float* X    = (const float*)d_in[0];
    const float* W[4]  = {(const float*)d_in[1],(const float*)d_in[4],(const float*)d_in[7],(const float*)d_in[10]};
    const float* wc[4] = {(const float*)d_in[2],(const float*)d_in[5],(const float*)d_in[8],(const float*)d_in[11]};
    const float* bb[4] = {(const float*)d_in[3],(const float*)d_in[6],(const float*)d_in[9],(const float*)d_in[12]};
    const float* Wcls = (const float*)d_in[13];
    const float* bcls = (const float*)d_in[14];
    float* out = (float*)d_out;

    // workspace layout:
    //   xA    bf16[16384*1024]  @ 0           33,554,432
    //   xB    bf16[16384*1024]  @ 33554432    33,554,432
    //   dxT   f32 [8*2048]      @ 67108864        65,536
    //   carry f32 [8192]        @ 67174400        32,768
    //   Wt0-2 bf16[3072*1024]   @ 67207168    3 x 6,291,456
    //   Ucb   f32 [C*2*8*1536]  @ 86081536    C*98,304   (C: 64..2048)
    char*  ws    = (char*)d_ws;
    bf16*  xA    = (bf16*)ws;
    bf16*  xB    = (bf16*)(ws + 33554432);
    float* dxT   = (float*)(ws + 67108864);
    float* carry = (float*)(ws + 67174400);
    bf16*  Wt[3] = {(bf16*)(ws + 67207168), (bf16*)(ws + 73498624), (bf16*)(ws + 79790080)};
    float* Ucb   = (float*)(ws + 86081536);
    const size_t NEEDED = 86081536ull + 64ull*98304ull;

    if (ws_size < NEEDED){
        float code = 1.0e6f + (float)((ws_size >> 20) > 9999 ? 9999 : (ws_size >> 20)) * 100.0f;
        k_code<<<1, 64, 0, stream>>>(out, code);
        return;
    }

    int C = 2048;
    while (C > 64 && 86081536ull + (size_t)C*98304ull > ws_size) C >>= 1;

    k_diff  <<<(NROWS+255)/256, 256, 0, stream>>>(X, dxT);
    for (int i = 0; i < 3; ++i)
        k_wt<<<dim3(32,96), 256, 0, stream>>>(W[i+1], Wt[i]);
    k_layer0<<<32, 256, 0, stream>>>(dxT, W[0], wc[0], bb[0], xA);

    bf16* xin = xA; bf16* xo = xB;
    for (int layer = 1; layer < 4; ++layer){
        for (int l0 = 0; l0 < L_SEQ; l0 += C){
            dim3 g(C*8/128, NHALF/128, 2);
            k_gemm<<<g, 256, 0, stream>>>(xin, Wt[layer-1], Ucb, l0, C);
            k_rec <<<128, 64, 0, stream>>>(Ucb, xin, xo, carry, wc[layer], bb[layer], l0, C);
        }
        bf16* t = xin; xin = xo; xo = t;
    }
    k_cls<<<NROWS/4, 256, 0, stream>>>(xin, Wcls, bcls, out);
}

// Round 8
// 2002.958 us; speedup vs baseline: 1.1435x; 1.0598x over previous
//
#include <hip/hip_runtime.h>
#include <hip/hip_bf16.h>

typedef __hip_bfloat16 bf16;
typedef unsigned short u16x8 __attribute__((ext_vector_type(8)));
using v8s = __attribute__((ext_vector_type(8))) short;   // bf16 x8 MFMA frag (4 VGPR)
using v4f = __attribute__((ext_vector_type(4))) float;   // f32 x4 acc frag

#define L_SEQ 2048
#define BATCH 8
#define NIN   1024    // 2H
#define WLD   3072    // W row stride, layers 1-3
#define NHALF 1536    // per-direction columns (3*H)
#define NROWS (L_SEQ*BATCH)

__device__ __forceinline__ float bits2f(unsigned short u){ return __uint_as_float(((unsigned)u)<<16); }
__device__ __forceinline__ float b2f(bf16 v){ return __bfloat162float(v); }
__device__ __forceinline__ bf16  f2b(float v){ return __float2bfloat16(v); }
__device__ __forceinline__ float sigm(float z){ return __fdividef(1.0f, 1.0f + __expf(-z)); }

__device__ __forceinline__ void gload16(const void* g, void* l){
    __builtin_amdgcn_global_load_lds((const __attribute__((address_space(1))) void*)g,
                                     (__attribute__((address_space(3))) void*)l, 16, 0, 0);
}

__global__ void k_code(float* __restrict__ out, float v){
    if (threadIdx.x == 0 && blockIdx.x == 0) out[0] = v;
}

// ---------------- dxT[b][l] = X[b][l] - X[b][l-1], 0 at l=0  ((B,L) layout)
__global__ __launch_bounds__(256) void k_diff(const float* __restrict__ X, float* __restrict__ dxT){
    int i = blockIdx.x*256 + threadIdx.x;
    if (i >= NROWS) return;
    int l = i & (L_SEQ-1);
    float v = 0.f;
    if (l > 0) v = X[i] - X[i-1];
    dxT[i] = v;
}

// ---------------- W (fp32 [1024][3072]) -> Wt (bf16 [3072][1024], transposed)
__global__ __launch_bounds__(256) void k_wt(const float* __restrict__ W, bf16* __restrict__ Wt){
    __shared__ float t[32][33];
    int k0 = blockIdx.x*32, n0 = blockIdx.y*32;
    int tx = threadIdx.x & 31, ty = threadIdx.x >> 5;   // ty 0..7
    #pragma unroll
    for (int j=0;j<4;j++)
        t[ty*4+j][tx] = W[(size_t)(k0+ty*4+j)*WLD + n0 + tx];
    __syncthreads();
    #pragma unroll
    for (int j=0;j<4;j++)
        Wt[(size_t)(n0+ty*4+j)*NIN + k0 + tx] = f2b(t[tx][ty*4+j]);
}

// ---------------- layer 0 (n_in=1, k=4): outer-product U, fused; LDS dx + pinned 8-ahead prefetch
__global__ __launch_bounds__(256) void k_layer0(const float* __restrict__ dxT, const float* __restrict__ W0,
                                                const float* __restrict__ wc, const float* __restrict__ bb,
                                                bf16* __restrict__ xout){
    __shared__ float sdx[L_SEQ];
    int g = blockIdx.x*256 + threadIdx.x;           // 8192 threads: (d,b,h); b,d block-uniform
    int h = g & 511, b = (g>>9) & 7, d = g >> 12;
    const float* dxp = dxT + b*L_SEQ;
    for (int t = threadIdx.x; t < L_SEQ; t += 256) sdx[t] = dxp[t];
    __syncthreads();

    int dcol = d*512 + h;
    float w0 = W0[d*2048 + h];
    float w1 = W0[d*2048 + 512 + h];
    float w2 = W0[d*2048 + 1024 + h];
    float w3 = W0[d*2048 + 1536 + h];
    float vf = wc[dcol],  vr = wc[1024 + dcol];
    float bfv = bb[dcol], brv = bb[1024 + dcol];
    float c = 0.f;

#define LD0(buf, s0) do{                                             \
        _Pragma("unroll")                                            \
        for (int i_=0;i_<8;i_++){                                    \
            int ss_ = (s0)+i_; if (ss_ > L_SEQ-1) ss_ = L_SEQ-1;     \
            buf[i_] = sdx[d ? (L_SEQ-1-ss_) : ss_];                  \
        }                                                            \
        __builtin_amdgcn_sched_barrier(0);                           \
    }while(0)

#define STEP0(s_, xv_) do{                                           \
        float u0_ = (xv_)*w0;                                        \
        float f_ = sigm((xv_)*w1 + vf*c + bfv);                      \
        c = f_*c + (1.f-f_)*u0_;                                     \
        float r_ = sigm((xv_)*w2 + vr*c + brv);                      \
        float hv_ = r_*c + (1.f-r_)*((xv_)*w3);                      \
        int t_ = d ? (L_SEQ-1-(s_)) : (s_);                          \
        xout[((size_t)t_*BATCH + b)*NIN + dcol] = f2b(hv_);          \
    }while(0)

    float xa[8], xb[8];
    LD0(xa, 0);
    for (int s0 = 0; s0 < L_SEQ; s0 += 16){
        LD0(xb, s0+8);
        #pragma unroll
        for (int i=0;i<8;i++) STEP0(s0+i, xa[i]);
        LD0(xa, s0+16);
        #pragma unroll
        for (int i=0;i<8;i++) STEP0(s0+8+i, xb[i]);
    }
#undef LD0
#undef STEP0
}

// ---------------- MFMA GEMM: Uc[set s] = x[chunk rows] @ Wt[set s]^T
// 128x128 tile, BK=32, 4 waves, 16x16x32 MFMA; 2-phase double-buffered LDS:
// stage tile k+1 issued BEFORE compute on tile k; single vmcnt(0)+barrier per iter.
__global__ __launch_bounds__(256) void k_gemm(const bf16* __restrict__ Xin, const bf16* __restrict__ Wt,
                                              float* __restrict__ Uc, int l0, int C){
    __shared__ bf16 As[2][4096];   // [buf][128 m][32 k], 64B rows (8 KB per buf)
    __shared__ bf16 Bs[2][4096];
    int tid = threadIdx.x;
    int lane = tid & 63;
    int s = blockIdx.z;
    int base = (s == 0) ? l0 : (L_SEQ - l0 - C);
    const bf16* A  = Xin + (size_t)base*BATCH*NIN;
    const bf16* Bm = Wt + (size_t)s*NHALF*NIN;
    float*      Cc = Uc + (size_t)s*(size_t)C*BATCH*NHALF;

    int m0 = blockIdx.x*128, n0 = blockIdx.y*128;
    int wv = tid >> 6;                  // wave 0..3
    int wm = (wv >> 1)*64, wn = (wv & 1)*64;

    v4f acc[4][4];
    #pragma unroll
    for (int i=0;i<4;i++)
        #pragma unroll
        for (int j=0;j<4;j++)
            #pragma unroll
            for (int r=0;r<4;r++) acc[i][j][r] = 0.f;

    int row_a = tid >> 2, kb = (tid & 3)*8;
    int wbase = (tid & 192)*16;                    // wave-uniform lds byte base
    int fro = (lane & 15)*64 + (lane >> 4)*16;

#define STAGE(q, k0) do{                                                        \
        char* la_ = (char*)As[q]; char* lb_ = (char*)Bs[q];                     \
        gload16(A  + (size_t)(m0 + row_a      )*NIN + (k0) + kb, la_ + wbase);  \
        gload16(A  + (size_t)(m0 + row_a + 64 )*NIN + (k0) + kb, la_ + 4096 + wbase); \
        gload16(Bm + (size_t)(n0 + row_a      )*NIN + (k0) + kb, lb_ + wbase);  \
        gload16(Bm + (size_t)(n0 + row_a + 64 )*NIN + (k0) + kb, lb_ + 4096 + wbase); \
    }while(0)

    STAGE(0, 0);
    __syncthreads();                    // drains vmcnt(0): tile 0 resident
    int cur = 0;
    for (int k0 = 0; k0 < NIN; k0 += 32){
        if (k0 + 32 < NIN) STAGE(cur^1, k0 + 32);   // prefetch next tile
        __builtin_amdgcn_sched_barrier(0);          // pin: stage issued before ds_read/MFMA
        const char* la = (const char*)As[cur];
        const char* lb = (const char*)Bs[cur];
        v8s av[4], bv[4];
        #pragma unroll
        for (int i=0;i<4;i++) av[i] = *(const v8s*)(la + (wm + i*16)*64 + fro);
        #pragma unroll
        for (int j=0;j<4;j++) bv[j] = *(const v8s*)(lb + (wn + j*16)*64 + fro);
        #pragma unroll
        for (int i=0;i<4;i++)
            #pragma unroll
            for (int j=0;j<4;j++)
                acc[i][j] = __builtin_amdgcn_mfma_f32_16x16x32_bf16(av[i], bv[j], acc[i][j], 0, 0, 0);
        __syncthreads();                // drains vmcnt(0) (prefetch) + lgkm; next iter reads cur^1
        cur ^= 1;
    }
#undef STAGE

    int cr = (lane >> 4)*4, ccol = lane & 15;
    #pragma unroll
    for (int i=0;i<4;i++){
        #pragma unroll
        for (int j=0;j<4;j++){
            size_t rb = (size_t)(m0 + wm + i*16 + cr)*NHALF + (n0 + wn + j*16 + ccol);
            #pragma unroll
            for (int r=0;r<4;r++) Cc[rb + (size_t)r*NHALF] = acc[i][j][r];
        }
    }
}

// ---------------- recurrence, layers 1-3 (k=3): clamp-free affine streams, pinned 16-ahead prefetch
__global__ __launch_bounds__(64) void k_rec(const float* __restrict__ Uc, const bf16* __restrict__ xin,
                                            bf16* __restrict__ xout, float* __restrict__ carry,
                                            const float* __restrict__ wc, const float* __restrict__ bb,
                                            int l0, int C){
    int g = blockIdx.x*64 + threadIdx.x;            // 8192 channels: (d,b,h)
    int h = g & 511, b = (g>>9) & 7, d = g >> 12;
    int dcol = d*512 + h;
    float vf = wc[dcol],   vr = wc[1024 + dcol];
    float bfv = bb[dcol],  brv = bb[1024 + dcol];
    float c = (l0 == 0) ? 0.f : carry[g];

    const float* u0p = Uc + (size_t)d*(size_t)C*12288 + (size_t)b*NHALF + h
                          + (d ? (size_t)(C-1)*12288 : 0);
    ptrdiff_t us = d ? -12288 : 12288;
    int t0 = d ? (L_SEQ-1 - l0) : l0;
    const bf16* xp = xin  + ((size_t)t0*BATCH + b)*NIN + dcol;
    bf16*       xq = xout + ((size_t)t0*BATCH + b)*NIN + dcol;
    ptrdiff_t xs = d ? -(BATCH*NIN) : (BATCH*NIN);

#define LOADG(B0,B1,B2,BR,s0) do{                                    \
        _Pragma("unroll")                                            \
        for (int i_=0;i_<16;i_++){                                   \
            const float* up_ = u0p + (ptrdiff_t)((s0)+i_)*us;        \
            B0[i_] = up_[0]; B1[i_] = up_[512]; B2[i_] = up_[1024];  \
            BR[i_] = b2f(xp[(ptrdiff_t)((s0)+i_)*xs]);               \
        }                                                            \
        __builtin_amdgcn_sched_barrier(0);                           \
    }while(0)

#define STEPG(B0,B1,B2,BR,s0) do{                                    \
        _Pragma("unroll")                                            \
        for (int i_=0;i_<16;i_++){                                   \
            float f_ = sigm(B1[i_] + vf*c + bfv);                    \
            c = f_*c + (1.f-f_)*B0[i_];                              \
            float r_ = sigm(B2[i_] + vr*c + brv);                    \
            float hv_ = r_*c + (1.f-r_)*BR[i_];                      \
            xq[(ptrdiff_t)((s0)+i_)*xs] = f2b(hv_);                  \
        } }while(0)

    float A0[16],A1[16],A2[16],AR[16];
    float B0[16],B1[16],B2[16],BR[16];
    LOADG(A0,A1,A2,AR, 0);
    int s0 = 0;
    for (; s0 + 64 <= C; s0 += 32){
        LOADG(B0,B1,B2,BR, s0+16);
        STEPG(A0,A1,A2,AR, s0);
        LOADG(A0,A1,A2,AR, s0+32);
        STEPG(B0,B1,B2,BR, s0+16);
    }
    LOADG(B0,B1,B2,BR, C-16);
    STEPG(A0,A1,A2,AR, C-32);
    STEPG(B0,B1,B2,BR, C-16);
    carry[g] = c;
#undef LOADG
#undef STEPG
}

// ---------------- classifier: out[(b*L + l)*3 + j] = h[row l*8+b] @ Wcls + bcls
__global__ __launch_bounds__(256) void k_cls(const bf16* __restrict__ Xf, const float* __restrict__ Wc,
                                             const float* __restrict__ bc, float* __restrict__ out){
    int wave = threadIdx.x >> 6, lane = threadIdx.x & 63;
    int row = blockIdx.x*4 + wave;                  // row = l*8+b
    const bf16* xp = Xf + (size_t)row*NIN + lane*16;
    u16x8 v0 = *(const u16x8*)(xp);
    u16x8 v1 = *(const u16x8*)(xp + 8);
    float a0=0.f, a1=0.f, a2=0.f;
    #pragma unroll
    for (int i=0;i<16;i++){
        float xv = bits2f(i<8 ? v0[i&7] : v1[i&7]);
        int k = lane*16 + i;
        a0 += xv*Wc[k*3+0];
        a1 += xv*Wc[k*3+1];
        a2 += xv*Wc[k*3+2];
    }
    #pragma unroll
    for (int off=32; off; off>>=1){
        a0 += __shfl_down(a0, off);
        a1 += __shfl_down(a1, off);
        a2 += __shfl_down(a2, off);
    }
    if (lane == 0){
        int l = row >> 3, b = row & 7;
        float* op = out + ((size_t)b*L_SEQ + l)*3;
        op[0] = a0 + bc[0];
        op[1] = a1 + bc[1];
        op[2] = a2 + bc[2];
    }
}

// ----------------------------------------------------------------
extern "C" void kernel_launch(void* const* d_in, const int* in_sizes, int n_in,
                              void* d_out, int out_size, void* d_ws, size_t ws_size,
                              hipStream_t stream){
    (void)in_sizes; (void)n_in; (void)out_size;
    const float* X    = (const float*)d_in[0];
    const float* W[4]  = {(const float*)d_in[1],(const float*)d_in[4],(const float*)d_in[7],(const float*)d_in[10]};
    const float* wc[4] = {(const float*)d_in[2],(const float*)d_in[5],(const float*)d_in[8],(const float*)d_in[11]};
    const float* bb[4] = {(const float*)d_in[3],(const float*)d_in[6],(const float*)d_in[9],(const float*)d_in[12]};
    const float* Wcls = (const float*)d_in[13];
    const float* bcls = (const float*)d_in[14];
    float* out = (float*)d_out;

    // workspace layout:
    //   xA    bf16[16384*1024]  @ 0           33,554,432
    //   xB    bf16[16384*1024]  @ 33554432    33,554,432
    //   dxT   f32 [8*2048]      @ 67108864        65,536
    //   carry f32 [8192]        @ 67174400        32,768
    //   Wt0-2 bf16[3072*1024]   @ 67207168    3 x 6,291,456
    //   Ucb   f32 [C*2*8*1536]  @ 86081536    C*98,304   (C: 64..2048)
    char*  ws    = (char*)d_ws;
    bf16*  xA    = (bf16*)ws;
    bf16*  xB    = (bf16*)(ws + 33554432);
    float* dxT   = (float*)(ws + 67108864);
    float* carry = (float*)(ws + 67174400);
    bf16*  Wt[3] = {(bf16*)(ws + 67207168), (bf16*)(ws + 73498624), (bf16*)(ws + 79790080)};
    float* Ucb   = (float*)(ws + 86081536);
    const size_t NEEDED = 86081536ull + 64ull*98304ull;

    if (ws_size < NEEDED){
        float code = 1.0e6f + (float)((ws_size >> 20) > 9999 ? 9999 : (ws_size >> 20)) * 100.0f;
        k_code<<<1, 64, 0, stream>>>(out, code);
        return;
    }

    int C = 2048;
    while (C > 64 && 86081536ull + (size_t)C*98304ull > ws_size) C >>= 1;

    k_diff  <<<(NROWS+255)/256, 256, 0, stream>>>(X, dxT);
    for (int i = 0; i < 3; ++i)
        k_wt<<<dim3(32,96), 256, 0, stream>>>(W[i+1], Wt[i]);
    k_layer0<<<32, 256, 0, stream>>>(dxT, W[0], wc[0], bb[0], xA);

    bf16* xin = xA; bf16* xo = xB;
    for (int layer = 1; layer < 4; ++layer){
        for (int l0 = 0; l0 < L_SEQ; l0 += C){
            dim3 g(C*8/128, NHALF/128, 2);
            k_gemm<<<g, 256, 0, stream>>>(xin, Wt[layer-1], Ucb, l0, C);
            k_rec <<<128, 64, 0, stream>>>(Ucb, xin, xo, carry, wc[layer], bb[layer], l0, C);
        }
        bf16* t = xin; xin = xo; xo = t;
    }
    k_cls<<<NROWS/4, 256, 0, stream>>>(xin, Wcls, bcls, out);
}